// Round 1
// baseline (241.562 us; speedup 1.0000x reference)
//
#include <hip/hip_runtime.h>

// y = x @ (W * M)^T where M is the identity mask -> y[b,d] = x[b,d] * W[d,d]*M[d,d].
// Pure HBM-bound elementwise scale: 134 MB read + 134 MB write ~= 43 us floor.

#define DDIM 2048
#define BDIM 16384

// Kernel 1: pull the (masked) diagonal of W into contiguous workspace.
// Strided reads (stride D+1 floats) but only 2048 of them -- negligible.
__global__ void extract_diag_kernel(const float* __restrict__ W,
                                    const float* __restrict__ M,
                                    float* __restrict__ diag) {
    int d = blockIdx.x * blockDim.x + threadIdx.x;
    if (d < DDIM) {
        size_t idx = (size_t)d * (DDIM + 1);
        diag[d] = W[idx] * M[idx];
    }
}

// Kernel 2: out[b,d] = x[b,d] * diag[d], float4-vectorized.
// D=2048 divisible by 4, so each float4 stays within one row's d-range.
__global__ void diag_scale_kernel(const float* __restrict__ x,
                                  const float* __restrict__ diag,
                                  float* __restrict__ out) {
    size_t t = (size_t)blockIdx.x * blockDim.x + threadIdx.x;
    size_t i4 = t * 4;  // flat float index, 4 per thread
    int d = (int)(i4 & (DDIM - 1));  // column index (D power of 2)

    float4 xv = *reinterpret_cast<const float4*>(x + i4);
    float4 wv = *reinterpret_cast<const float4*>(diag + d);

    float4 o;
    o.x = xv.x * wv.x;
    o.y = xv.y * wv.y;
    o.z = xv.z * wv.z;
    o.w = xv.w * wv.w;

    *reinterpret_cast<float4*>(out + i4) = o;
}

extern "C" void kernel_launch(void* const* d_in, const int* in_sizes, int n_in,
                              void* d_out, int out_size, void* d_ws, size_t ws_size,
                              hipStream_t stream) {
    const float* x = (const float*)d_in[0];
    const float* W = (const float*)d_in[1];
    const float* M = (const float*)d_in[2];
    float* out = (float*)d_out;
    float* diag = (float*)d_ws;  // 2048 floats = 8 KB scratch

    // Extract diagonal (one small block-set).
    extract_diag_kernel<<<(DDIM + 255) / 256, 256, 0, stream>>>(W, M, diag);

    // Elementwise scale: B*D/4 float4 lanes.
    const size_t total4 = (size_t)BDIM * DDIM / 4;  // 8,388,608
    const int block = 256;
    const int grid = (int)((total4 + block - 1) / block);  // 32768 blocks
    diag_scale_kernel<<<grid, block, 0, stream>>>(x, diag, out);
}